// Round 8
// baseline (1988.048 us; speedup 1.0000x reference)
//
#include <hip/hip_runtime.h>
#include <hip/hip_bf16.h>
#include <stdint.h>

#define TT 8192      // tokens = B*S
#define DD 2048      // hidden
#define EE 16        // experts
#define FF 1408      // moe intermediate
#define FSH 2048     // shared intermediate
#define BM 128
#define BN 64
#define BK 64
#define MAXT 272     // 32768/128 + 16 partials
#define LISTN 32768

typedef __bf16 bf16;
typedef __bf16 bf16x8 __attribute__((ext_vector_type(8)));
typedef __bf16 bf16x4v __attribute__((ext_vector_type(4)));
typedef float f32x4 __attribute__((ext_vector_type(4)));

__device__ __forceinline__ void async16(void* lds, const void* g) {
  __builtin_amdgcn_global_load_lds((const __attribute__((address_space(1))) unsigned int*)g,
                                   (__attribute__((address_space(3))) unsigned int*)lds, 16, 0, 0);
}

#define MEMFENCE __asm__ volatile("" ::: "memory")
#define BAR() do { MEMFENCE; __builtin_amdgcn_s_barrier(); MEMFENCE; } while (0)
#define WAITV(n) __asm__ volatile("s_waitcnt vmcnt(" #n ")" ::: "memory")
#define MFMA16(a,b,c) __builtin_amdgcn_mfma_f32_16x16x32_bf16(a,b,c,0,0,0)

// T1 chunked XCD swizzle (bijective when nblk%8==0; all grids here comply)
__device__ __forceinline__ void xcd_swz(int& bx, int& by) {
  int nx = gridDim.x, nblk = nx * gridDim.y;
  int L = blockIdx.y * nx + blockIdx.x;
  if ((nblk & 7) == 0) {
    int T = (L & 7) * (nblk >> 3) + (L >> 3);
    bx = T % nx; by = T / nx;
  } else { bx = blockIdx.x; by = blockIdx.y; }
}

// T2 swizzle (both-sides-or-neither with global_load_lds, rule #21):
// stage: thread t fetches src chunk (t&7)^((t>>3)&7) of its row into its
// linear LDS slot; read: row r chunk c lives at chunk c^(r&7).
__device__ __forceinline__ bf16x8 ldfrag(const bf16* p, int r, int kk, int ln) {
  return *(const bf16x8*)&p[r*BK + ((((kk)*4 + (ln>>4)) ^ (ln&7))<<3)];
}

// ---------------- small kernels ----------------

__global__ void k_zero(int* __restrict__ counts) {
  int i = threadIdx.x;
  if (i < EE) counts[i] = 0;
}

__global__ void k_cvt_x(const float* __restrict__ x, bf16* __restrict__ xb) {
  long i = ((long)blockIdx.x*256 + threadIdx.x)*4;
  float4 v = *(const float4*)(x + i);
  bf16x4v o = { (bf16)v.x, (bf16)v.y, (bf16)v.z, (bf16)v.w };
  *(bf16x4v*)(xb + i) = o;
}

// transpose+convert(+scale): in f32 [R][C] -> out bf16 [phys(C)][R].
// imode=0: phys(c)=c. imode=1 (g/u interleave): phys(c)=(c>>4)*32+(c&15)+hoff,
// so 16-col groups of g (hoff=0) and u (hoff=16) alternate in the output.
__global__ void k_cvt_T2(const float* __restrict__ in, bf16* __restrict__ outp,
                         const int R, const int C, const float* __restrict__ sc,
                         const long inStride, const long outStride,
                         const int imode, const int hoff) {
  __shared__ float t[64][65];
  int b = blockIdx.z;
  float s = sc ? sc[b] : 1.f;
  const float* ib = in + (long)b*inStride;
  bf16* ob = outp + (long)b*outStride;
  int c0 = blockIdx.x*64, r0 = blockIdx.y*64;
  int tid = threadIdx.x;           // 256 threads
  int rr = tid>>4, cc = (tid&15)*4;
  #pragma unroll
  for (int j=0;j<4;j++) {
    float4 v = *(const float4*)(ib + (long)(r0+rr+16*j)*C + c0+cc);
    t[rr+16*j][cc]=v.x; t[rr+16*j][cc+1]=v.y; t[rr+16*j][cc+2]=v.z; t[rr+16*j][cc+3]=v.w;
  }
  __syncthreads();
  int oc = tid>>3, ch = (tid&7)*8;
  #pragma unroll
  for (int j=0;j<2;j++) {
    int c = oc + 32*j;
    int cg = c0 + c;
    long pr = imode ? ((long)(cg>>4)*32 + (cg&15) + hoff) : (long)cg;
    bf16 tmp[8];
    #pragma unroll
    for (int i=0;i<8;i++) tmp[i] = (bf16)(t[ch+i][c]*s);
    *(bf16x8*)(ob + pr*R + r0 + ch) = *(bf16x8*)tmp;
  }
}

__global__ void k_router(const float* __restrict__ x, const float* __restrict__ wr,
                         int* __restrict__ topki, float* __restrict__ topkp,
                         int* __restrict__ counts) {
  int wv = threadIdx.x >> 6, ln = threadIdx.x & 63;
  int t = blockIdx.x*4 + wv;
  int e = ln & 15, c = ln >> 4;
  const float* xr = x + (long)t*DD;
  float s = 0.f;
  for (int k = c*512; k < (c+1)*512; k++)
    s = fmaf(xr[k], wr[k*EE + e], s);
  s += __shfl_xor(s, 16);
  s += __shfl_xor(s, 32);
  float l[EE];
  #pragma unroll
  for (int j=0;j<EE;j++) l[j] = __shfl(s, j);
  float mx = l[0];
  #pragma unroll
  for (int j=1;j<EE;j++) mx = fmaxf(mx, l[j]);
  float p[EE];
  #pragma unroll
  for (int j=0;j<EE;j++) p[j] = __expf(l[j]-mx);
  float pv[4]; int pi[4]; unsigned used = 0;
  #pragma unroll
  for (int k2=0;k2<4;k2++) {
    float best = -1.f; int bi = 0;
    #pragma unroll
    for (int j=0;j<EE;j++) {
      bool ok = (((used>>j)&1u)==0u) && (p[j] > best);
      best = ok ? p[j] : best; bi = ok ? j : bi;
    }
    pv[k2]=best; pi[k2]=bi; used |= (1u<<bi);
  }
  float s4 = pv[0]+pv[1]+pv[2]+pv[3];
  if (ln==0) {
    #pragma unroll
    for (int k2=0;k2<4;k2++) {
      topki[t*4+k2] = pi[k2];
      topkp[t*4+k2] = pv[k2]/s4;
      atomicAdd(&counts[pi[k2]], 1);
    }
  }
}

__global__ void k_offsets(const int* __restrict__ counts, int* __restrict__ offs,
                          int* __restrict__ cursors, int2* __restrict__ tiles,
                          int* __restrict__ ntiles) {
  if (threadIdx.x==0) {
    int o=0, nt=0;
    for (int e=0;e<EE;e++) {
      offs[e]=o; cursors[e]=o;
      int cnt=counts[e];
      for (int s2=0;s2<cnt;s2+=BM) {
        int rw = cnt-s2; if (rw>BM) rw=BM;
        tiles[nt].x = o+s2; tiles[nt].y = e | (rw<<8); nt++;
      }
      o += cnt;
    }
    offs[EE]=o; ntiles[0]=nt;
  }
}

__global__ void k_scatter(const int* __restrict__ topki, int* __restrict__ cursors,
                          int* __restrict__ list, int* __restrict__ inv) {
  int t = blockIdx.x*256 + threadIdx.x;
  if (t >= TT) return;
  #pragma unroll
  for (int k2=0;k2<4;k2++) {
    int e = topki[t*4+k2];
    int pos = atomicAdd(&cursors[e], 1);
    list[pos] = t*4+k2;
    inv[t*4+k2] = pos;
  }
}

// final combine: out[t][:] += sum_k Hd[inv[t*4+k]][:]  (Hd pre-scaled)
__global__ void k_combine(const bf16* __restrict__ hd, const int* __restrict__ inv,
                          float* __restrict__ out) {
  int t = blockIdx.x;
  long c = (long)threadIdx.x*8;
  int4 iv = *(const int4*)(inv + t*4);
  float s[8];
  #pragma unroll
  for (int i=0;i<8;i++) s[i]=0.f;
  int rows4[4] = {iv.x, iv.y, iv.z, iv.w};
  #pragma unroll
  for (int k=0;k<4;k++) {
    bf16x8 v = *(const bf16x8*)(hd + (long)rows4[k]*DD + c);
    #pragma unroll
    for (int i=0;i<8;i++) s[i] += (float)v[i];
  }
  float* o = out + (long)t*DD + c;
  float4 a = *(float4*)o, b = *(float4*)(o+4);
  a.x+=s[0]; a.y+=s[1]; a.z+=s[2]; a.w+=s[3];
  b.x+=s[4]; b.y+=s[5]; b.z+=s[6]; b.w+=s[7];
  *(float4*)o = a; *(float4*)(o+4) = b;
}

// ======== fused gate+up GEMM with g/u-INTERLEAVED B: 128x64, 3 blocks/CU =====
// B has N'=2C rows (16-row g/u groups). Block covers 64 N'-rows = 32 f-cols.
// Wave wn: n-frag0 = g, n-frag1 = u of f = n0/2 + wn*16 + (ln&15).
// Hout[slot][f] = silu(g)*u.
__global__ __launch_bounds__(256,3)
void k_gemm_gu(const bf16* __restrict__ A, const bf16* __restrict__ Bb,
               bf16* __restrict__ Hout,
               const int2* __restrict__ tiles, const int* __restrict__ ntiles,
               const int* __restrict__ list,
               const int Kdim, const int Nstr, const long strideB, const int gather) {
  __shared__ __align__(16) bf16 sA[2][BM*BK];   // 32 KB
  __shared__ __align__(16) bf16 sB[2][BN*BK];   // 16 KB
  __shared__ int sRow[BM];
  __shared__ int sSlot[BM];

  int bx, by; xcd_swz(bx, by);
  const int tid = threadIdx.x, wv = tid>>6, ln = tid&63;
  int start, rows, eidx = 0;
  if (gather) {
    if (by >= ntiles[0]) return;
    int2 td = tiles[by];
    start = td.x; eidx = td.y & 0xff; rows = td.y >> 8;
  } else { start = by*BM; rows = BM; }

  if (tid < BM) {
    int entry = gather ? ((tid < rows) ? list[start+tid] : 0) : (start+tid);
    sSlot[tid] = entry;
    sRow[tid]  = gather ? (entry>>2) : entry;
  }
  __syncthreads();

  const char* Ac = (const char*)A;
  const char* Bc = (const char*)(Bb + (long)eidx*strideB);
  const long Kb = (long)Kdim*2;
  const int n0 = bx*BN;

  const long scol = (long)((((ln)&7) ^ (((ln)>>3)&7))*16);
  long aoff[4];
  #pragma unroll
  for (int i=0;i<4;i++) { int r = i*32 + wv*8 + (ln>>3); aoff[i] = (long)sRow[r]*Kb + scol; }
  long boff[2];
  #pragma unroll
  for (int i=0;i<2;i++) { long n = n0 + i*32 + wv*8 + (ln>>3); boff[i] = n*Kb + scol; }

  f32x4 acc[4][2];
  f32x4 z = {0.f,0.f,0.f,0.f};
  #pragma unroll
  for (int m=0;m<4;m++) { acc[m][0]=z; acc[m][1]=z; }

  const int wm = wv>>1, wn = wv&1;
  const int nk = Kdim/BK;

  #pragma unroll
  for (int i=0;i<4;i++) async16(&sA[0][i*2048 + wv*512], Ac + aoff[i]);
  #pragma unroll
  for (int i=0;i<2;i++) async16(&sB[0][i*2048 + wv*512], Bc + boff[i]);

  int cur = 0;
  for (int kt=0; kt<nk; kt++) {
    if (kt+1 < nk) {
      const long kb = (long)(kt+1)*(BK*2);
      #pragma unroll
      for (int i=0;i<4;i++) async16(&sA[cur^1][i*2048 + wv*512], Ac + aoff[i] + kb);
      #pragma unroll
      for (int i=0;i<2;i++) async16(&sB[cur^1][i*2048 + wv*512], Bc + boff[i] + kb);
      WAITV(6);
    } else {
      WAITV(0);
    }
    BAR();
    #pragma unroll
    for (int kk=0; kk<2; kk++) {
      bf16x8 af[4], bf[2];
      #pragma unroll
      for (int m=0;m<4;m++) af[m] = ldfrag(sA[cur], wm*64 + m*16 + (ln&15), kk, ln);
      #pragma unroll
      for (int n=0;n<2;n++) bf[n] = ldfrag(sB[cur], wn*32 + n*16 + (ln&15), kk, ln);
      #pragma unroll
      for (int m=0;m<4;m++)
        #pragma unroll
        for (int n=0;n<2;n++)
          acc[m][n] = MFMA16(af[m], bf[n], acc[m][n]);
    }
    BAR();
    cur ^= 1;
  }

  // epilogue: pair n-frag0 (g) with n-frag1 (u) -> one f column set per wave
  const int fcol = (n0>>1) + wn*16 + (ln&15);
  #pragma unroll
  for (int m=0;m<4;m++) {
    #pragma unroll
    for (int i2=0;i2<4;i2++) {
      int r = wm*64 + m*16 + (ln>>4)*4 + i2;
      if (r < rows) {
        float g = acc[m][0][i2], u = acc[m][1][i2];
        float h = g/(1.f + __expf(-g)) * u;
        Hout[(long)sSlot[r]*Nstr + fcol] = (bf16)h;
      }
    }
  }
}

// ============ down GEMM: 128x64, 3 blocks/CU ================================
// mode 0: plain store out[row][col] = v            (shared expert)
// mode 1: atomicAdd(out[token][col], 2.5*p*v)      (routed, small-ws fallback)
// mode 2: hd[slot][col] = bf16(2.5*p*v)            (routed, combine later)
__global__ __launch_bounds__(256,3)
void k_gemm_down(const bf16* __restrict__ A, const bf16* __restrict__ Bb,
                 float* __restrict__ out, bf16* __restrict__ hd,
                 const int2* __restrict__ tiles, const int* __restrict__ ntiles,
                 const int* __restrict__ list, const float* __restrict__ topkp,
                 const int Kdim, const long strideB, const int mode) {
  __shared__ __align__(16) bf16 sA[2][BM*BK];
  __shared__ __align__(16) bf16 sB[2][BN*BK];
  __shared__ int sSlot[BM];

  int bx, by; xcd_swz(bx, by);
  const int tid = threadIdx.x, wv = tid>>6, ln = tid&63;
  int start, rows, eidx = 0;
  if (mode) {
    if (by >= ntiles[0]) return;
    int2 td = tiles[by];
    start = td.x; eidx = td.y & 0xff; rows = td.y >> 8;
  } else { start = by*BM; rows = BM; }

  if (tid < BM) sSlot[tid] = mode ? ((tid < rows) ? list[start+tid] : 0) : (start+tid);
  __syncthreads();

  const char* Ac = (const char*)A;
  const char* Bc = (const char*)(Bb + (long)eidx*strideB);
  const long Kb = (long)Kdim*2;
  const int n0 = bx*BN;

  const long scol = (long)((((ln)&7) ^ (((ln)>>3)&7))*16);
  long aoff[4];
  #pragma unroll
  for (int i=0;i<4;i++) { int r = i*32 + wv*8 + (ln>>3); aoff[i] = (long)sSlot[r]*Kb + scol; }
  long boff[2];
  #pragma unroll
  for (int i=0;i<2;i++) { long n = n0 + i*32 + wv*8 + (ln>>3); boff[i] = n*Kb + scol; }

  f32x4 acc[4][2];
  f32x4 z = {0.f,0.f,0.f,0.f};
  #pragma unroll
  for (int m=0;m<4;m++) { acc[m][0]=z; acc[m][1]=z; }

  const int wm = wv>>1, wn = wv&1;
  const int nk = Kdim/BK;

  #pragma unroll
  for (int i=0;i<4;i++) async16(&sA[0][i*2048 + wv*512], Ac + aoff[i]);
  #pragma unroll
  for (int i=0;i<2;i++) async16(&sB[0][i*2048 + wv*512], Bc + boff[i]);

  int cur = 0;
  for (int kt=0; kt<nk; kt++) {
    if (kt+1 < nk) {
      const long kb = (long)(kt+1)*(BK*2);
      #pragma unroll
      for (int i=0;i<4;i++) async16(&sA[cur^1][i*2048 + wv*512], Ac + aoff[i] + kb);
      #pragma unroll
      for (int i=0;i<2;i++) async16(&sB[cur^1][i*2048 + wv*512], Bc + boff[i] + kb);
      WAITV(6);
    } else {
      WAITV(0);
    }
    BAR();
    #pragma unroll
    for (int kk=0; kk<2; kk++) {
      bf16x8 af[4], bf[2];
      #pragma unroll
      for (int m=0;m<4;m++) af[m] = ldfrag(sA[cur], wm*64 + m*16 + (ln&15), kk, ln);
      #pragma unroll
      for (int n=0;n<2;n++) bf[n] = ldfrag(sB[cur], wn*32 + n*16 + (ln&15), kk, ln);
      #pragma unroll
      for (int m=0;m<4;m++)
        #pragma unroll
        for (int n=0;n<2;n++)
          acc[m][n] = MFMA16(af[m], bf[n], acc[m][n]);
    }
    BAR();
    cur ^= 1;
  }

  #pragma unroll
  for (int m=0;m<4;m++) {
    #pragma unroll
    for (int i2=0;i2<4;i2++) {
      int r = wm*64 + m*16 + (ln>>4)*4 + i2;
      if (r < rows) {
        if (mode == 2) {
          int slot = sSlot[r];
          float wgt = 2.5f * topkp[slot];
          long rb = (long)(start+r)*DD;
          #pragma unroll
          for (int n=0;n<2;n++)
            hd[rb + n0 + wn*32 + n*16 + (ln&15)] = (bf16)(wgt*acc[m][n][i2]);
        } else if (mode == 1) {
          int slot = sSlot[r];
          int t = slot>>2;
          float wgt = 2.5f * topkp[slot];
          #pragma unroll
          for (int n=0;n<2;n++)
            atomicAdd(out + (long)t*DD + n0 + wn*32 + n*16 + (ln&15), wgt*acc[m][n][i2]);
        } else {
          long rb = (long)(start+r)*DD;
          #pragma unroll
          for (int n=0;n<2;n++)
            out[rb + n0 + wn*32 + n*16 + (ln&15)] = acc[m][n][i2];
        }
      }
    }
  }
}

// ---------------- host ----------------
extern "C" void kernel_launch(void* const* d_in, const int* in_sizes, int n_in,
                              void* d_out, int out_size, void* d_ws, size_t ws_size,
                              hipStream_t stream) {
  (void)in_sizes; (void)n_in; (void)out_size;
  const float* x   = (const float*)d_in[0];
  const float* wr  = (const float*)d_in[1];
  const float* wg  = (const float*)d_in[2];
  const float* wu  = (const float*)d_in[3];
  const float* wd  = (const float*)d_in[4];
  const float* sg  = (const float*)d_in[5];
  const float* su  = (const float*)d_in[6];
  const float* sd  = (const float*)d_in[7];
  const float* swg = (const float*)d_in[8];
  const float* swu = (const float*)d_in[9];
  const float* swd = (const float*)d_in[10];
  float* out = (float*)d_out;

  char* base = (char*)d_ws;
  size_t off = 0;
  auto alloc = [&](size_t b) { char* p = base + off; off += (b + 255) & ~(size_t)255; return p; };

  int*   topki   = (int*)  alloc((size_t)TT*4*sizeof(int));
  float* topkp   = (float*)alloc((size_t)TT*4*sizeof(float));
  int*   inv     = (int*)  alloc((size_t)TT*4*sizeof(int));
  int*   counts  = (int*)  alloc(EE*sizeof(int));
  int*   offs    = (int*)  alloc(32*sizeof(int));
  int*   cursors = (int*)  alloc(EE*sizeof(int));
  int*   ntiles  = (int*)  alloc(2*sizeof(int));
  int2*  tiles   = (int2*) alloc(MAXT*sizeof(int2));
  int*   list    = (int*)  alloc((size_t)LISTN*sizeof(int));
  bf16*  xb      = (bf16*) alloc((size_t)TT*DD*2);
  bf16*  Wgu     = (bf16*) alloc((size_t)EE*2*FF*DD*2);  // interleaved g/u; later aliased by Wd_t
  bf16*  Sgu     = (bf16*) alloc((size_t)2*FSH*DD*2);    // shared g/u interleaved
  bf16*  swd_t   = (bf16*) alloc((size_t)FSH*DD*2);
  bf16*  W3      = (bf16*) alloc((size_t)LISTN*FF*2);    // Hs (early) then H
  bf16*  Hd      = (bf16*) alloc((size_t)TT*4*DD*2);     // routed-down rows (big-ws mode)
  const bool big_ws = (off <= ws_size);
  const int  dmode  = big_ws ? 2 : 1;

  bf16* Wd_t = Wgu;       // reuses Wgu space after routed gu completes (stream-ordered)
  bf16* Hs = W3;
  bf16* H  = W3;

  k_zero<<<1, 64, 0, stream>>>(counts);
  k_cvt_x<<<(TT*DD)/1024, 256, 0, stream>>>(x, xb);

  // shared-expert weights: g/u -> interleaved Sgu [2*FSH][DD]; swd -> [DD][FSH]
  k_cvt_T2<<<dim3(FSH/64, DD/64, 1), 256, 0, stream>>>(swg, Sgu, DD, FSH, nullptr, 0, 0, 1, 0);
  k_cvt_T2<<<dim3(FSH/64, DD/64, 1), 256, 0, stream>>>(swu, Sgu, DD, FSH, nullptr, 0, 0, 1, 16);
  k_cvt_T2<<<dim3(DD/64, FSH/64, 1), 256, 0, stream>>>(swd, swd_t, FSH, DD, nullptr, 0, 0, 0, 0);

  // shared expert: gate/up -> Hs ; down -> out (plain stores)
  k_gemm_gu<<<dim3(2*FSH/BN, TT/BM), 256, 0, stream>>>(xb, Sgu, Hs,
      nullptr, nullptr, nullptr, DD, FSH, 0, 0);
  k_gemm_down<<<dim3(DD/BN, TT/BM), 256, 0, stream>>>(Hs, swd_t, out, nullptr,
      nullptr, nullptr, nullptr, nullptr, FSH, 0, 0);

  // router -> topk -> expert-sorted assignment list + tile table (+inverse)
  k_router<<<TT/4, 256, 0, stream>>>(x, wr, topki, topkp, counts);
  k_offsets<<<1, 64, 0, stream>>>(counts, offs, cursors, tiles, ntiles);
  k_scatter<<<TT/256, 256, 0, stream>>>(topki, cursors, list, inv);

  // routed expert weights: g/u -> interleaved Wgu [2*FF][DD] per expert
  k_cvt_T2<<<dim3(FF/64, DD/64, EE), 256, 0, stream>>>(wg, Wgu, DD, FF, sg,
      (long)DD*FF, (long)2*FF*DD, 1, 0);
  k_cvt_T2<<<dim3(FF/64, DD/64, EE), 256, 0, stream>>>(wu, Wgu, DD, FF, su,
      (long)DD*FF, (long)2*FF*DD, 1, 16);

  // routed gate/up (gathered rows) -> H[assignment][F]
  k_gemm_gu<<<dim3(2*FF/BN, MAXT), 256, 0, stream>>>(xb, Wgu, H,
      tiles, ntiles, list, DD, FF, (long)2*FF*DD, 1);

  // Wd transpose (reuses Wgu space after gu done reading it)
  k_cvt_T2<<<dim3(DD/64, FF/64, EE), 256, 0, stream>>>(wd, Wd_t, FF, DD, sd,
      (long)FF*DD, (long)DD*FF, 0, 0);

  // routed down: mode2 -> pre-scaled rows into Hd (no atomics); mode1 fallback
  k_gemm_down<<<dim3(DD/BN, MAXT), 256, 0, stream>>>(H, Wd_t, out, Hd,
      tiles, ntiles, list, topkp, FF, (long)DD*FF, dmode);

  if (big_ws)
    k_combine<<<TT, 256, 0, stream>>>(Hd, inv, out);
}

// Round 9
// 1811.652 us; speedup vs baseline: 1.0974x; 1.0974x over previous
//
#include <hip/hip_runtime.h>
#include <hip/hip_bf16.h>
#include <stdint.h>

#define TT 8192      // tokens = B*S
#define DD 2048      // hidden
#define EE 16        // experts
#define FF 1408      // moe intermediate
#define FSH 2048     // shared intermediate
#define BM 128
#define BN 128
#define BK 64
#define MAXT 272     // 32768/128 + 16 partials
#define LISTN 32768

typedef __bf16 bf16;
typedef __bf16 bf16x8 __attribute__((ext_vector_type(8)));
typedef __bf16 bf16x4v __attribute__((ext_vector_type(4)));
typedef float f32x4 __attribute__((ext_vector_type(4)));

__device__ __forceinline__ void async16(void* lds, const void* g) {
  __builtin_amdgcn_global_load_lds((const __attribute__((address_space(1))) unsigned int*)g,
                                   (__attribute__((address_space(3))) unsigned int*)lds, 16, 0, 0);
}

#define MEMFENCE __asm__ volatile("" ::: "memory")
#define BAR() do { MEMFENCE; __builtin_amdgcn_s_barrier(); MEMFENCE; } while (0)
#define WAITV(n) __asm__ volatile("s_waitcnt vmcnt(" #n ")" ::: "memory")
#define MFMA16(a,b,c) __builtin_amdgcn_mfma_f32_16x16x32_bf16(a,b,c,0,0,0)

// T1 chunked XCD swizzle (bijective when nblk%8==0; all grids here comply)
__device__ __forceinline__ void xcd_swz(int& bx, int& by) {
  int nx = gridDim.x, nblk = nx * gridDim.y;
  int L = blockIdx.y * nx + blockIdx.x;
  if ((nblk & 7) == 0) {
    int T = (L & 7) * (nblk >> 3) + (L >> 3);
    bx = T % nx; by = T / nx;
  } else { bx = blockIdx.x; by = blockIdx.y; }
}

// T2 swizzle (both-sides-or-neither with global_load_lds, rule #21):
// stage: thread t fetches src chunk (t&7)^((t>>3)&7) of its row into its
// linear LDS slot; read: row r chunk c lives at chunk c^(r&7).
__device__ __forceinline__ bf16x8 ldfrag(const bf16* p, int r, int kk, int ln) {
  return *(const bf16x8*)&p[r*BK + ((((kk)*4 + (ln>>4)) ^ (ln&7))<<3)];
}

// ---------------- small kernels ----------------

__global__ void k_zero(int* __restrict__ counts) {
  int i = threadIdx.x;
  if (i < EE) counts[i] = 0;
}

__global__ void k_cvt_x(const float* __restrict__ x, bf16* __restrict__ xb) {
  long i = ((long)blockIdx.x*256 + threadIdx.x)*4;
  float4 v = *(const float4*)(x + i);
  bf16x4v o = { (bf16)v.x, (bf16)v.y, (bf16)v.z, (bf16)v.w };
  *(bf16x4v*)(xb + i) = o;
}

// transpose+convert(+scale): in f32 [R][C] -> out bf16 [phys(C)][R].
// imode=0: phys(c)=c. imode=1 (g/u interleave): phys(c)=(c>>4)*32+(c&15)+hoff.
__global__ void k_cvt_T2(const float* __restrict__ in, bf16* __restrict__ outp,
                         const int R, const int C, const float* __restrict__ sc,
                         const long inStride, const long outStride,
                         const int imode, const int hoff) {
  __shared__ float t[64][65];
  int b = blockIdx.z;
  float s = sc ? sc[b] : 1.f;
  const float* ib = in + (long)b*inStride;
  bf16* ob = outp + (long)b*outStride;
  int c0 = blockIdx.x*64, r0 = blockIdx.y*64;
  int tid = threadIdx.x;           // 256 threads
  int rr = tid>>4, cc = (tid&15)*4;
  #pragma unroll
  for (int j=0;j<4;j++) {
    float4 v = *(const float4*)(ib + (long)(r0+rr+16*j)*C + c0+cc);
    t[rr+16*j][cc]=v.x; t[rr+16*j][cc+1]=v.y; t[rr+16*j][cc+2]=v.z; t[rr+16*j][cc+3]=v.w;
  }
  __syncthreads();
  int oc = tid>>3, ch = (tid&7)*8;
  #pragma unroll
  for (int j=0;j<2;j++) {
    int c = oc + 32*j;
    int cg = c0 + c;
    long pr = imode ? ((long)(cg>>4)*32 + (cg&15) + hoff) : (long)cg;
    bf16 tmp[8];
    #pragma unroll
    for (int i=0;i<8;i++) tmp[i] = (bf16)(t[ch+i][c]*s);
    *(bf16x8*)(ob + pr*R + r0 + ch) = *(bf16x8*)tmp;
  }
}

__global__ void k_router(const float* __restrict__ x, const float* __restrict__ wr,
                         int* __restrict__ topki, float* __restrict__ topkp,
                         int* __restrict__ counts) {
  int wv = threadIdx.x >> 6, ln = threadIdx.x & 63;
  int t = blockIdx.x*4 + wv;
  int e = ln & 15, c = ln >> 4;
  const float* xr = x + (long)t*DD;
  float s = 0.f;
  for (int k = c*512; k < (c+1)*512; k++)
    s = fmaf(xr[k], wr[k*EE + e], s);
  s += __shfl_xor(s, 16);
  s += __shfl_xor(s, 32);
  float l[EE];
  #pragma unroll
  for (int j=0;j<EE;j++) l[j] = __shfl(s, j);
  float mx = l[0];
  #pragma unroll
  for (int j=1;j<EE;j++) mx = fmaxf(mx, l[j]);
  float p[EE];
  #pragma unroll
  for (int j=0;j<EE;j++) p[j] = __expf(l[j]-mx);
  float pv[4]; int pi[4]; unsigned used = 0;
  #pragma unroll
  for (int k2=0;k2<4;k2++) {
    float best = -1.f; int bi = 0;
    #pragma unroll
    for (int j=0;j<EE;j++) {
      bool ok = (((used>>j)&1u)==0u) && (p[j] > best);
      best = ok ? p[j] : best; bi = ok ? j : bi;
    }
    pv[k2]=best; pi[k2]=bi; used |= (1u<<bi);
  }
  float s4 = pv[0]+pv[1]+pv[2]+pv[3];
  if (ln==0) {
    #pragma unroll
    for (int k2=0;k2<4;k2++) {
      topki[t*4+k2] = pi[k2];
      topkp[t*4+k2] = pv[k2]/s4;
      atomicAdd(&counts[pi[k2]], 1);
    }
  }
}

__global__ void k_offsets(const int* __restrict__ counts, int* __restrict__ offs,
                          int* __restrict__ cursors, int2* __restrict__ tiles,
                          int* __restrict__ ntiles) {
  if (threadIdx.x==0) {
    int o=0, nt=0;
    for (int e=0;e<EE;e++) {
      offs[e]=o; cursors[e]=o;
      int cnt=counts[e];
      for (int s2=0;s2<cnt;s2+=BM) {
        int rw = cnt-s2; if (rw>BM) rw=BM;
        tiles[nt].x = o+s2; tiles[nt].y = e | (rw<<8); nt++;
      }
      o += cnt;
    }
    offs[EE]=o; ntiles[0]=nt;
  }
}

__global__ void k_scatter(const int* __restrict__ topki, int* __restrict__ cursors,
                          int* __restrict__ list, int* __restrict__ inv) {
  int t = blockIdx.x*256 + threadIdx.x;
  if (t >= TT) return;
  #pragma unroll
  for (int k2=0;k2<4;k2++) {
    int e = topki[t*4+k2];
    int pos = atomicAdd(&cursors[e], 1);
    list[pos] = t*4+k2;
    inv[t*4+k2] = pos;
  }
}

// final combine: out[t][:] += sum_k Hd[inv[t*4+k]][:]  (Hd pre-scaled)
__global__ void k_combine(const bf16* __restrict__ hd, const int* __restrict__ inv,
                          float* __restrict__ out) {
  int t = blockIdx.x;
  long c = (long)threadIdx.x*8;
  int4 iv = *(const int4*)(inv + t*4);
  float s[8];
  #pragma unroll
  for (int i=0;i<8;i++) s[i]=0.f;
  int rows4[4] = {iv.x, iv.y, iv.z, iv.w};
  #pragma unroll
  for (int k=0;k<4;k++) {
    bf16x8 v = *(const bf16x8*)(hd + (long)rows4[k]*DD + c);
    #pragma unroll
    for (int i=0;i<8;i++) s[i] += (float)v[i];
  }
  float* o = out + (long)t*DD + c;
  float4 a = *(float4*)o, b = *(float4*)(o+4);
  a.x+=s[0]; a.y+=s[1]; a.z+=s[2]; a.w+=s[3];
  b.x+=s[4]; b.y+=s[5]; b.z+=s[6]; b.w+=s[7];
  *(float4*)o = a; *(float4*)(o+4) = b;
}

// ======== fused gate+up GEMM, g/u-interleaved B: 128x128, 4 waves ===========
// m103 config: wave tile 64x64, acc[4][4], 32 MFMA per barrier-pair.
// B rows are 16-col g/u groups; wave wn covers 4 n-frags = 2 (g,u) pairs.
__global__ __launch_bounds__(256,2)
void k_gemm_gu(const bf16* __restrict__ A, const bf16* __restrict__ Bb,
               bf16* __restrict__ Hout,
               const int2* __restrict__ tiles, const int* __restrict__ ntiles,
               const int* __restrict__ list,
               const int Kdim, const int Nstr, const long strideB, const int gather) {
  __shared__ __align__(16) bf16 sA[2][BM*BK];   // 32 KB
  __shared__ __align__(16) bf16 sB[2][BN*BK];   // 32 KB
  __shared__ int sRow[BM];
  __shared__ int sSlot[BM];

  int bx, by; xcd_swz(bx, by);
  const int tid = threadIdx.x, wv = tid>>6, ln = tid&63;
  int start, rows, eidx = 0;
  if (gather) {
    if (by >= ntiles[0]) return;
    int2 td = tiles[by];
    start = td.x; eidx = td.y & 0xff; rows = td.y >> 8;
  } else { start = by*BM; rows = BM; }

  if (tid < BM) {
    int entry = gather ? ((tid < rows) ? list[start+tid] : 0) : (start+tid);
    sSlot[tid] = entry;
    sRow[tid]  = gather ? (entry>>2) : entry;
  }
  __syncthreads();

  const char* Ac = (const char*)A;
  const char* Bc = (const char*)(Bb + (long)eidx*strideB);
  const long Kb = (long)Kdim*2;
  const int n0 = bx*BN;
  const int l15 = ln & 15;

  const long scol = (long)((((tid)&7) ^ ((tid>>3)&7))*16);
  long aoff[4];
  #pragma unroll
  for (int i=0;i<4;i++) { int r = i*32 + (tid>>3); aoff[i] = (long)sRow[r]*Kb + scol; }
  long boff[4];
  #pragma unroll
  for (int i=0;i<4;i++) { long n = n0 + i*32 + (tid>>3); boff[i] = n*Kb + scol; }

  f32x4 acc[4][4];
  f32x4 z = {0.f,0.f,0.f,0.f};
  #pragma unroll
  for (int m=0;m<4;m++)
    #pragma unroll
    for (int n=0;n<4;n++) acc[m][n]=z;

  const int wm = wv>>1, wn = wv&1;   // 2x2 waves, 64x64 each
  const int nk = Kdim/BK;

  #pragma unroll
  for (int i=0;i<4;i++) async16(&sA[0][i*2048 + wv*512], Ac + aoff[i]);
  #pragma unroll
  for (int i=0;i<4;i++) async16(&sB[0][i*2048 + wv*512], Bc + boff[i]);

  int cur = 0;
  for (int kt=0; kt<nk; kt++) {
    if (kt+1 < nk) {
      const long kb = (long)(kt+1)*(BK*2);
      #pragma unroll
      for (int i=0;i<4;i++) async16(&sA[cur^1][i*2048 + wv*512], Ac + aoff[i] + kb);
      #pragma unroll
      for (int i=0;i<4;i++) async16(&sB[cur^1][i*2048 + wv*512], Bc + boff[i] + kb);
      WAITV(8);
    } else {
      WAITV(0);
    }
    BAR();
    #pragma unroll
    for (int kk=0; kk<2; kk++) {
      bf16x8 af[4], bf[4];
      #pragma unroll
      for (int m=0;m<4;m++) af[m] = ldfrag(sA[cur], wm*64 + m*16 + l15, kk, ln);
      #pragma unroll
      for (int n=0;n<4;n++) bf[n] = ldfrag(sB[cur], wn*64 + n*16 + l15, kk, ln);
      #pragma unroll
      for (int m=0;m<4;m++)
        #pragma unroll
        for (int n=0;n<4;n++)
          acc[m][n] = MFMA16(af[m], bf[n], acc[m][n]);
    }
    BAR();
    cur ^= 1;
  }

  // epilogue: n-frag pairs (2j, 2j+1) = (g,u) of f-block j
  #pragma unroll
  for (int m=0;m<4;m++) {
    #pragma unroll
    for (int i2=0;i2<4;i2++) {
      int r = wm*64 + m*16 + (ln>>4)*4 + i2;
      if (r < rows) {
        long orow = (long)sSlot[r]*Nstr;
        #pragma unroll
        for (int j=0;j<2;j++) {
          float g = acc[m][2*j][i2], u = acc[m][2*j+1][i2];
          float h = g/(1.f + __expf(-g)) * u;
          Hout[orow + (n0>>1) + wn*32 + j*16 + l15] = (bf16)h;
        }
      }
    }
  }
}

// ============ down GEMM: 128x128, 4 waves (m103 config) ======================
// mode 0: plain store out[row][col] = v            (shared expert)
// mode 1: atomicAdd(out[token][col], 2.5*p*v)      (routed, small-ws fallback)
// mode 2: hd[slot][col] = bf16(2.5*p*v)            (routed, combine later)
__global__ __launch_bounds__(256,2)
void k_gemm_down(const bf16* __restrict__ A, const bf16* __restrict__ Bb,
                 float* __restrict__ out, bf16* __restrict__ hd,
                 const int2* __restrict__ tiles, const int* __restrict__ ntiles,
                 const int* __restrict__ list, const float* __restrict__ topkp,
                 const int Kdim, const long strideB, const int mode) {
  __shared__ __align__(16) bf16 sA[2][BM*BK];
  __shared__ __align__(16) bf16 sB[2][BN*BK];
  __shared__ int sSlot[BM];

  int bx, by; xcd_swz(bx, by);
  const int tid = threadIdx.x, wv = tid>>6, ln = tid&63;
  int start, rows, eidx = 0;
  if (mode) {
    if (by >= ntiles[0]) return;
    int2 td = tiles[by];
    start = td.x; eidx = td.y & 0xff; rows = td.y >> 8;
  } else { start = by*BM; rows = BM; }

  if (tid < BM) sSlot[tid] = mode ? ((tid < rows) ? list[start+tid] : 0) : (start+tid);
  __syncthreads();

  const char* Ac = (const char*)A;
  const char* Bc = (const char*)(Bb + (long)eidx*strideB);
  const long Kb = (long)Kdim*2;
  const int n0 = bx*BN;
  const int l15 = ln & 15;

  const long scol = (long)((((tid)&7) ^ ((tid>>3)&7))*16);
  long aoff[4];
  #pragma unroll
  for (int i=0;i<4;i++) { int r = i*32 + (tid>>3); aoff[i] = (long)sSlot[r]*Kb + scol; }
  long boff[4];
  #pragma unroll
  for (int i=0;i<4;i++) { long n = n0 + i*32 + (tid>>3); boff[i] = n*Kb + scol; }

  f32x4 acc[4][4];
  f32x4 z = {0.f,0.f,0.f,0.f};
  #pragma unroll
  for (int m=0;m<4;m++)
    #pragma unroll
    for (int n=0;n<4;n++) acc[m][n]=z;

  const int wm = wv>>1, wn = wv&1;
  const int nk = Kdim/BK;

  #pragma unroll
  for (int i=0;i<4;i++) async16(&sA[0][i*2048 + wv*512], Ac + aoff[i]);
  #pragma unroll
  for (int i=0;i<4;i++) async16(&sB[0][i*2048 + wv*512], Bc + boff[i]);

  int cur = 0;
  for (int kt=0; kt<nk; kt++) {
    if (kt+1 < nk) {
      const long kb = (long)(kt+1)*(BK*2);
      #pragma unroll
      for (int i=0;i<4;i++) async16(&sA[cur^1][i*2048 + wv*512], Ac + aoff[i] + kb);
      #pragma unroll
      for (int i=0;i<4;i++) async16(&sB[cur^1][i*2048 + wv*512], Bc + boff[i] + kb);
      WAITV(8);
    } else {
      WAITV(0);
    }
    BAR();
    #pragma unroll
    for (int kk=0; kk<2; kk++) {
      bf16x8 af[4], bf[4];
      #pragma unroll
      for (int m=0;m<4;m++) af[m] = ldfrag(sA[cur], wm*64 + m*16 + l15, kk, ln);
      #pragma unroll
      for (int n=0;n<4;n++) bf[n] = ldfrag(sB[cur], wn*64 + n*16 + l15, kk, ln);
      #pragma unroll
      for (int m=0;m<4;m++)
        #pragma unroll
        for (int n=0;n<4;n++)
          acc[m][n] = MFMA16(af[m], bf[n], acc[m][n]);
    }
    BAR();
    cur ^= 1;
  }

  #pragma unroll
  for (int m=0;m<4;m++) {
    #pragma unroll
    for (int i2=0;i2<4;i2++) {
      int r = wm*64 + m*16 + (ln>>4)*4 + i2;
      if (r < rows) {
        if (mode == 2) {
          int slot = sSlot[r];
          float wgt = 2.5f * topkp[slot];
          long rb = (long)(start+r)*DD;
          #pragma unroll
          for (int n=0;n<4;n++)
            hd[rb + n0 + wn*64 + n*16 + l15] = (bf16)(wgt*acc[m][n][i2]);
        } else if (mode == 1) {
          int slot = sSlot[r];
          int t = slot>>2;
          float wgt = 2.5f * topkp[slot];
          #pragma unroll
          for (int n=0;n<4;n++)
            atomicAdd(out + (long)t*DD + n0 + wn*64 + n*16 + l15, wgt*acc[m][n][i2]);
        } else {
          long rb = (long)(start+r)*DD;
          #pragma unroll
          for (int n=0;n<4;n++)
            out[rb + n0 + wn*64 + n*16 + l15] = acc[m][n][i2];
        }
      }
    }
  }
}

// ---------------- host ----------------
extern "C" void kernel_launch(void* const* d_in, const int* in_sizes, int n_in,
                              void* d_out, int out_size, void* d_ws, size_t ws_size,
                              hipStream_t stream) {
  (void)in_sizes; (void)n_in; (void)out_size;
  const float* x   = (const float*)d_in[0];
  const float* wr  = (const float*)d_in[1];
  const float* wg  = (const float*)d_in[2];
  const float* wu  = (const float*)d_in[3];
  const float* wd  = (const float*)d_in[4];
  const float* sg  = (const float*)d_in[5];
  const float* su  = (const float*)d_in[6];
  const float* sd  = (const float*)d_in[7];
  const float* swg = (const float*)d_in[8];
  const float* swu = (const float*)d_in[9];
  const float* swd = (const float*)d_in[10];
  float* out = (float*)d_out;

  char* base = (char*)d_ws;
  size_t off = 0;
  auto alloc = [&](size_t b) { char* p = base + off; off += (b + 255) & ~(size_t)255; return p; };

  int*   topki   = (int*)  alloc((size_t)TT*4*sizeof(int));
  float* topkp   = (float*)alloc((size_t)TT*4*sizeof(float));
  int*   inv     = (int*)  alloc((size_t)TT*4*sizeof(int));
  int*   counts  = (int*)  alloc(EE*sizeof(int));
  int*   offs    = (int*)  alloc(32*sizeof(int));
  int*   cursors = (int*)  alloc(EE*sizeof(int));
  int*   ntiles  = (int*)  alloc(2*sizeof(int));
  int2*  tiles   = (int2*) alloc(MAXT*sizeof(int2));
  int*   list    = (int*)  alloc((size_t)LISTN*sizeof(int));
  bf16*  xb      = (bf16*) alloc((size_t)TT*DD*2);
  bf16*  Wgu     = (bf16*) alloc((size_t)EE*2*FF*DD*2);  // interleaved g/u; later aliased by Wd_t
  bf16*  Sgu     = (bf16*) alloc((size_t)2*FSH*DD*2);    // shared g/u interleaved
  bf16*  swd_t   = (bf16*) alloc((size_t)FSH*DD*2);
  bf16*  W3      = (bf16*) alloc((size_t)LISTN*FF*2);    // Hs (early) then H
  bf16*  Hd      = (bf16*) alloc((size_t)TT*4*DD*2);     // routed-down rows (big-ws mode)
  const bool big_ws = (off <= ws_size);
  const int  dmode  = big_ws ? 2 : 1;

  bf16* Wd_t = Wgu;       // reuses Wgu space after routed gu completes (stream-ordered)
  bf16* Hs = W3;
  bf16* H  = W3;

  k_zero<<<1, 64, 0, stream>>>(counts);
  k_cvt_x<<<(TT*DD)/1024, 256, 0, stream>>>(x, xb);

  // shared-expert weights: g/u -> interleaved Sgu [2*FSH][DD]; swd -> [DD][FSH]
  k_cvt_T2<<<dim3(FSH/64, DD/64, 1), 256, 0, stream>>>(swg, Sgu, DD, FSH, nullptr, 0, 0, 1, 0);
  k_cvt_T2<<<dim3(FSH/64, DD/64, 1), 256, 0, stream>>>(swu, Sgu, DD, FSH, nullptr, 0, 0, 1, 16);
  k_cvt_T2<<<dim3(DD/64, FSH/64, 1), 256, 0, stream>>>(swd, swd_t, FSH, DD, nullptr, 0, 0, 0, 0);

  // shared expert: gate/up -> Hs ; down -> out (plain stores)
  k_gemm_gu<<<dim3(2*FSH/BN, TT/BM), 256, 0, stream>>>(xb, Sgu, Hs,
      nullptr, nullptr, nullptr, DD, FSH, 0, 0);
  k_gemm_down<<<dim3(DD/BN, TT/BM), 256, 0, stream>>>(Hs, swd_t, out, nullptr,
      nullptr, nullptr, nullptr, nullptr, FSH, 0, 0);

  // router -> topk -> expert-sorted assignment list + tile table (+inverse)
  k_router<<<TT/4, 256, 0, stream>>>(x, wr, topki, topkp, counts);
  k_offsets<<<1, 64, 0, stream>>>(counts, offs, cursors, tiles, ntiles);
  k_scatter<<<TT/256, 256, 0, stream>>>(topki, cursors, list, inv);

  // routed expert weights: g/u -> interleaved Wgu [2*FF][DD] per expert
  k_cvt_T2<<<dim3(FF/64, DD/64, EE), 256, 0, stream>>>(wg, Wgu, DD, FF, sg,
      (long)DD*FF, (long)2*FF*DD, 1, 0);
  k_cvt_T2<<<dim3(FF/64, DD/64, EE), 256, 0, stream>>>(wu, Wgu, DD, FF, su,
      (long)DD*FF, (long)2*FF*DD, 1, 16);

  // routed gate/up (gathered rows) -> H[assignment][F]
  k_gemm_gu<<<dim3(2*FF/BN, MAXT), 256, 0, stream>>>(xb, Wgu, H,
      tiles, ntiles, list, DD, FF, (long)2*FF*DD, 1);

  // Wd transpose (reuses Wgu space after gu done reading it)
  k_cvt_T2<<<dim3(DD/64, FF/64, EE), 256, 0, stream>>>(wd, Wd_t, FF, DD, sd,
      (long)FF*DD, (long)DD*FF, 0, 0);

  // routed down: mode2 -> pre-scaled rows into Hd (no atomics); mode1 fallback
  k_gemm_down<<<dim3(DD/BN, MAXT), 256, 0, stream>>>(H, Wd_t, out, Hd,
      tiles, ntiles, list, topkp, FF, (long)DD*FF, dmode);

  if (big_ws)
    k_combine<<<TT, 256, 0, stream>>>(Hd, inv, out);
}